// Round 7
// baseline (213.737 us; speedup 1.0000x reference)
//
#include <hip/hip_runtime.h>
#include <stdint.h>
#include <math.h>

#define B_ 4
#define E_ 1024
#define L_ 2048
#define H_ 16
#define DH_ 64
#define SCALE_ 0.03125f

typedef __bf16 bf16;
typedef __bf16 bf16x8 __attribute__((ext_vector_type(8)));
typedef __bf16 bf16x4 __attribute__((ext_vector_type(4)));
typedef float f32x4 __attribute__((ext_vector_type(4)));

__device__ __forceinline__ f32x4 mfma16(bf16x8 a, bf16x8 b, f32x4 c) {
  return __builtin_amdgcn_mfma_f32_16x16x32_bf16(a, b, c, 0, 0, 0);
}

// async global->LDS, 16B per lane. LDS dest = wave-uniform base + lane*16 (HW rule).
__device__ __forceinline__ void gl_lds16(const void* g, void* lds) {
  auto* lp = reinterpret_cast<__attribute__((address_space(3))) unsigned int*>(
      reinterpret_cast<uintptr_t>(lds));
  const auto* gp = reinterpret_cast<const __attribute__((address_space(1))) unsigned int*>(
      reinterpret_cast<uintptr_t>(g));
  __builtin_amdgcn_global_load_lds(gp, lp, 16, 0, 0);
}

// ---------------- transpose + f32->bf16 convert: out[c][r] = (bf16) in[r][c] ----------------
__global__ __launch_bounds__(256) void tconv(const float* __restrict__ in,
                                             bf16* __restrict__ out, int R, int C) {
  in  += (size_t)blockIdx.z * R * C;
  out += (size_t)blockIdx.z * R * C;
  __shared__ float t[32][33];
  const int r0 = blockIdx.x * 32, c0 = blockIdx.y * 32;
  const int lx = threadIdx.x & 31, ly = threadIdx.x >> 5;
#pragma unroll
  for (int q = 0; q < 4; q++)
    t[ly + q * 8][lx] = in[(size_t)(r0 + ly + q * 8) * C + c0 + lx];
  __syncthreads();
#pragma unroll
  for (int q = 0; q < 4; q++) {
    int c = ly + q * 8;
    out[(size_t)(c0 + c) * R + r0 + lx] = (bf16)t[lx][c];
  }
}

// both weight transposes in one launch (z selects the pair)
__global__ __launch_bounds__(256) void wconv(const float* __restrict__ in0,
                                             const float* __restrict__ in1,
                                             bf16* __restrict__ out0,
                                             bf16* __restrict__ out1) {
  const float* in = blockIdx.z ? in1 : in0;
  bf16* out = blockIdx.z ? out1 : out0;
  __shared__ float t[32][33];
  const int r0 = blockIdx.x * 32, c0 = blockIdx.y * 32;
  const int lx = threadIdx.x & 31, ly = threadIdx.x >> 5;
#pragma unroll
  for (int q = 0; q < 4; q++)
    t[ly + q * 8][lx] = in[(size_t)(r0 + ly + q * 8) * E_ + c0 + lx];
  __syncthreads();
#pragma unroll
  for (int q = 0; q < 4; q++) {
    int c = ly + q * 8;
    out[(size_t)(c0 + c) * E_ + r0 + lx] = (bf16)t[lx][c];
  }
}

// ---------------- GEMM: C[m][n] = sum_k A[m][k] * Bt[n][k]  (both bf16, K-contiguous) -------
// 3-buffer counted-vmcnt pipeline with RAW s_barrier (no implicit vmcnt(0) drain):
//   iter it: issue STAGE(it+2) -> compute buf(it%3) -> vmcnt(4) [tile it+1 landed,
//   it+2's 4 loads stay in flight] -> s_barrier.
template <int EPI>
__global__ __launch_bounds__(256) void gemm_bt(const bf16* __restrict__ A,
                                               const bf16* __restrict__ Bt,
                                               bf16* __restrict__ outT,
                                               bf16* __restrict__ outD,
                                               float* __restrict__ outF,
                                               const float* __restrict__ bias) {
  constexpr int M = E_, N = L_, K = E_;
  constexpr int NIT = K / 32;
  const int bm = blockIdx.x, bn = blockIdx.y, b = blockIdx.z;
  __shared__ bf16 As[3][128 * 32];
  __shared__ bf16 Bs[3][128 * 32];
  const int tid = threadIdx.x, w = tid >> 6, l = tid & 63;
  const int wm = (w >> 1) << 6, wn = (w & 1) << 6;
  const bf16* Ap = A + (size_t)bm * 128 * K;
  const bf16* Bp = Bt + (size_t)b * N * K + (size_t)bn * 128 * K;
  f32x4 acc[4][4] = {};
  const int g0 = (w * 2 + 0) * 64 + l, g1 = (w * 2 + 1) * 64 + l;
  const int r0 = g0 >> 2, s0 = (g0 & 3) ^ ((r0 >> 1) & 3);
  const int r1 = g1 >> 2, s1 = (g1 & 3) ^ ((r1 >> 1) & 3);

#define STAGE_G(kt_, buf)                                              \
  do {                                                                 \
    gl_lds16(Ap + (size_t)r0 * K + (kt_) + s0 * 8, &As[buf][g0 * 8]);  \
    gl_lds16(Ap + (size_t)r1 * K + (kt_) + s1 * 8, &As[buf][g1 * 8]);  \
    gl_lds16(Bp + (size_t)r0 * K + (kt_) + s0 * 8, &Bs[buf][g0 * 8]);  \
    gl_lds16(Bp + (size_t)r1 * K + (kt_) + s1 * 8, &Bs[buf][g1 * 8]);  \
  } while (0)

  STAGE_G(0, 0);
  STAGE_G(32, 1);
  asm volatile("s_waitcnt vmcnt(4)" ::: "memory");  // tile 0 landed; tile 1 in flight
  __builtin_amdgcn_s_barrier();
#pragma unroll 1
  for (int it = 0; it < NIT; it++) {
    const int cur = it - (it / 3) * 3;  // it % 3
    if (it + 2 < NIT) STAGE_G((it + 2) * 32, (it + 2) - ((it + 2) / 3) * 3);
    bf16x8 af[4], bfr[4];
#pragma unroll
    for (int fm = 0; fm < 4; fm++) {
      int row = wm + fm * 16 + (l & 15);
      int gg = row * 4 + ((l >> 4) ^ ((row >> 1) & 3));
      af[fm] = *(const bf16x8*)(&As[cur][gg * 8]);
    }
#pragma unroll
    for (int fn = 0; fn < 4; fn++) {
      int row = wn + fn * 16 + (l & 15);
      int gg = row * 4 + ((l >> 4) ^ ((row >> 1) & 3));
      bfr[fn] = *(const bf16x8*)(&Bs[cur][gg * 8]);
    }
#pragma unroll
    for (int fm = 0; fm < 4; fm++)
#pragma unroll
      for (int fn = 0; fn < 4; fn++)
        acc[fm][fn] = mfma16(af[fm], bfr[fn], acc[fm][fn]);
    if (it + 2 < NIT) {
      asm volatile("s_waitcnt vmcnt(4)" ::: "memory");  // next tile landed, 4 stay in flight
    } else if (it + 1 < NIT) {
      asm volatile("s_waitcnt vmcnt(0)" ::: "memory");  // tail: drain
    }
    __builtin_amdgcn_s_barrier();
  }
#undef STAGE_G
  const int cm = bm * 128 + wm, cn = bn * 128 + wn;
  if (EPI == 0) {
#pragma unroll
    for (int fn = 0; fn < 4; fn++) {
#pragma unroll
      for (int fm = 0; fm < 4; fm++) {
        int n = cn + fn * 16 + (l & 15);
        int m = cm + fm * 16 + ((l >> 4) << 2);
        f32x4 v = acc[fm][fn];
        bf16x4 pv = {(bf16)v[0], (bf16)v[1], (bf16)v[2], (bf16)v[3]};
        *(bf16x4*)(outT + (size_t)b * N * M + (size_t)n * M + m) = pv;
#pragma unroll
        for (int r = 0; r < 4; r++)
          outD[(size_t)b * M * N + (size_t)(m + r) * N + n] = pv[r];
      }
    }
  } else {
#pragma unroll
    for (int fm = 0; fm < 4; fm++) {
      int m = cm + fm * 16 + ((l >> 4) << 2);
#pragma unroll
      for (int r = 0; r < 4; r++) {
        float bv = bias[m + r];
#pragma unroll
        for (int fn = 0; fn < 4; fn++) {
          int n = cn + fn * 16 + (l & 15);
          outF[(size_t)b * M * N + (size_t)(m + r) * N + n] = acc[fm][fn][r] + bv;
        }
      }
    }
  }
}

// ---------------- flash attention (causal over keys i<=j, softmax over i) -------------------
// QBLK=128 (8 waves x 16 rows), dbuf K/V prefetch, zero in-loop cross-lane reduces.
__global__ __launch_bounds__(512) void attn(const bf16* __restrict__ kqvT,
                                            const bf16* __restrict__ kqvD,
                                            bf16* __restrict__ tT) {
  const int linear = (int)blockIdx.x + 16 * ((int)blockIdx.y + 16 * (int)blockIdx.z);
  const int qb = 15 - (linear >> 6);
  const int h = linear & 15, b = (linear >> 4) & 3;
  const int tid = threadIdx.x, w = tid >> 6, l = tid & 63;
  const int j0 = qb * 128 + w * 16;
  __shared__ bf16 Ks[2][64 * 64];
  __shared__ bf16 Vs[2][64 * 64];
  __shared__ bf16 Ps[8][16 * 64];
  const size_t bT = (size_t)b * L_ * E_;
  const size_t bD = (size_t)b * E_ * L_;
  bf16x8 qa[2];
  {
    size_t qoff = bT + (size_t)(j0 + (l & 15)) * E_ + h * 64 + ((l >> 4) << 3);
    qa[0] = *(const bf16x8*)(kqvT + qoff);
    qa[1] = *(const bf16x8*)(kqvT + qoff + 32);
#pragma unroll
    for (int e = 0; e < 8; e++) {  // fold scale into Q (2^-5 exact in bf16)
      qa[0][e] = (bf16)((float)qa[0][e] * SCALE_);
      qa[1][e] = (bf16)((float)qa[1][e] * SCALE_);
    }
  }
  float mrun[4] = {0.f, 0.f, 0.f, 0.f};   // deferred max, guard at +8
  float lsum[4] = {0.f, 0.f, 0.f, 0.f};   // per-lane partial row-sums
  f32x4 tacc[4] = {};
  bf16* myPs = &Ps[w][0];
  const int g = w * 64 + l;
  const int rS = g >> 3, sS = (g & 7) ^ (rS & 7);
  const int nch = 2 * (qb + 1);

#define STAGE(c, buf)                                                                  \
  do {                                                                                 \
    const int i0_ = (c) * 64;                                                          \
    gl_lds16(kqvT + bT + (size_t)(i0_ + rS) * E_ + h * 64 + sS * 8, &Ks[buf][g * 8]);  \
    gl_lds16(kqvD + bD + (size_t)(h * 64 + rS) * L_ + i0_ + sS * 8, &Vs[buf][g * 8]);  \
  } while (0)

  STAGE(0, 0);
  asm volatile("s_waitcnt vmcnt(0)" ::: "memory");
  __syncthreads();

#pragma unroll 1
  for (int c = 0; c < nch; c++) {
    const int cur = c & 1;
    if (c + 1 < nch) STAGE(c + 1, cur ^ 1);  // prefetch next tile
    const int i0 = c * 64;
    const bf16* Kc = &Ks[cur][0];
    const bf16* Vc = &Vs[cur][0];
    if (i0 <= j0 + 15) {  // wave-uniform: skip fully-masked tiles
      f32x4 sacc[4];
      __builtin_amdgcn_s_setprio(1);
#pragma unroll
      for (int fi = 0; fi < 4; fi++) {
        int row = fi * 16 + (l & 15);
        bf16x8 k0 = *(const bf16x8*)(Kc + row * 64 + (((l >> 4) ^ (row & 7)) << 3));
        bf16x8 k1 = *(const bf16x8*)(Kc + row * 64 + ((((l >> 4) + 4) ^ (row & 7)) << 3));
        f32x4 z = {};
        z = mfma16(qa[0], k0, z);
        z = mfma16(qa[1], k1, z);
        sacc[fi] = z;
      }
      __builtin_amdgcn_s_setprio(0);
      const int jrb = j0 + ((l >> 4) << 2);
      if (i0 + 63 > j0) {  // tile touches the diagonal: causal mask
#pragma unroll
        for (int fi = 0; fi < 4; fi++) {
          int i = i0 + fi * 16 + (l & 15);
#pragma unroll
          for (int r = 0; r < 4; r++)
            if (i > jrb + r) sacc[fi][r] = -INFINITY;
        }
      }
      bool ov = false;
#pragma unroll
      for (int fi = 0; fi < 4; fi++)
#pragma unroll
        for (int r = 0; r < 4; r++) ov |= (sacc[fi][r] > mrun[r] + 8.f);
      if (__any(ov)) {  // cold: true rescale (never taken for this data)
        float mx[4];
#pragma unroll
        for (int r = 0; r < 4; r++)
          mx[r] = fmaxf(fmaxf(sacc[0][r], sacc[1][r]), fmaxf(sacc[2][r], sacc[3][r]));
#pragma unroll
        for (int r = 0; r < 4; r++) {
          mx[r] = fmaxf(mx[r], __shfl_xor(mx[r], 1));
          mx[r] = fmaxf(mx[r], __shfl_xor(mx[r], 2));
          mx[r] = fmaxf(mx[r], __shfl_xor(mx[r], 4));
          mx[r] = fmaxf(mx[r], __shfl_xor(mx[r], 8));
        }
#pragma unroll
        for (int r = 0; r < 4; r++) {
          float mn = fmaxf(mrun[r], mx[r]);
          float a = __expf(mrun[r] - mn);
          lsum[r] *= a;
#pragma unroll
          for (int fd = 0; fd < 4; fd++) tacc[fd][r] *= a;
          mrun[r] = mn;
        }
      }
#pragma unroll
      for (int fi = 0; fi < 4; fi++) {
        int icol = fi * 16 + (l & 15);
#pragma unroll
        for (int r = 0; r < 4; r++) {
          float p = __expf(sacc[fi][r] - mrun[r]);
          lsum[r] += p;
          int jl = ((l >> 4) << 2) + r;
          int slot = (icol >> 3) ^ (jl & 7);
          myPs[jl * 64 + slot * 8 + (icol & 7)] = (bf16)p;
        }
      }
      bf16x8 pa[2];
      {
        int jl = l & 15;
#pragma unroll
        for (int kc = 0; kc < 2; kc++)
          pa[kc] = *(const bf16x8*)(myPs + jl * 64 + (((kc * 4 + (l >> 4)) ^ (jl & 7)) << 3));
      }
      __builtin_amdgcn_s_setprio(1);
#pragma unroll
      for (int fd = 0; fd < 4; fd++) {
        int row = fd * 16 + (l & 15);
#pragma unroll
        for (int kc = 0; kc < 2; kc++) {
          bf16x8 vf = *(const bf16x8*)(Vc + row * 64 + (((kc * 4 + (l >> 4)) ^ (row & 7)) << 3));
          tacc[fd] = mfma16(pa[kc], vf, tacc[fd]);
        }
      }
      __builtin_amdgcn_s_setprio(0);
    }
    asm volatile("s_waitcnt vmcnt(0)" ::: "memory");  // prefetch landed
    __syncthreads();
  }
#undef STAGE
#pragma unroll
  for (int r = 0; r < 4; r++) {
    lsum[r] += __shfl_xor(lsum[r], 1);
    lsum[r] += __shfl_xor(lsum[r], 2);
    lsum[r] += __shfl_xor(lsum[r], 4);
    lsum[r] += __shfl_xor(lsum[r], 8);
  }
#pragma unroll
  for (int r = 0; r < 4; r++) {
    int j = j0 + ((l >> 4) << 2) + r;
    float inv = 1.0f / lsum[r];
#pragma unroll
    for (int fd = 0; fd < 4; fd++) {
      int d = fd * 16 + (l & 15);
      tT[bT + (size_t)j * E_ + h * 64 + d] = (bf16)(tacc[fd][r] * inv);
    }
  }
}

extern "C" void kernel_launch(void* const* d_in, const int* in_sizes, int n_in,
                              void* d_out, int out_size, void* d_ws, size_t ws_size,
                              hipStream_t stream) {
  const float* x     = (const float*)d_in[0];
  const float* Wqkv  = (const float*)d_in[1];
  const float* Wproj = (const float*)d_in[2];
  const float* bias  = (const float*)d_in[3];
  float* out = (float*)d_out;
  char* ws = (char*)d_ws;
  bf16* Wt_qkv  = (bf16*)ws;                         // 2 MB
  bf16* Wt_proj = (bf16*)(ws + (2ull << 20));        // 2 MB
  bf16* xT      = (bf16*)(ws + (4ull << 20));        // 16 MB (reused as tT)
  bf16* kqvT    = (bf16*)(ws + (20ull << 20));       // 16 MB
  bf16* kqvD    = (bf16*)(ws + (36ull << 20));       // 16 MB  -> total 52 MB
  bf16* tT      = xT;                                // alias: xT dead after gemm1

  wconv<<<dim3(32, 32, 2), 256, 0, stream>>>(Wqkv, Wproj, Wt_qkv, Wt_proj);
  tconv<<<dim3(32, 64, B_), 256, 0, stream>>>(x, xT, E_, L_);
  gemm_bt<0><<<dim3(8, 16, B_), 256, 0, stream>>>(Wt_qkv, xT, kqvT, kqvD,
                                                  (float*)nullptr, (const float*)nullptr);
  attn<<<dim3(16, 16, B_), 512, 0, stream>>>(kqvT, kqvD, tT);
  gemm_bt<1><<<dim3(8, 16, B_), 256, 0, stream>>>(Wt_proj, tT, (bf16*)nullptr,
                                                  (bf16*)nullptr, out, bias);
}

// Round 8
// 210.906 us; speedup vs baseline: 1.0134x; 1.0134x over previous
//
#include <hip/hip_runtime.h>
#include <stdint.h>
#include <math.h>

#define B_ 4
#define E_ 1024
#define L_ 2048
#define H_ 16
#define DH_ 64
#define SCALE_ 0.03125f

typedef __bf16 bf16;
typedef __bf16 bf16x8 __attribute__((ext_vector_type(8)));
typedef __bf16 bf16x4 __attribute__((ext_vector_type(4)));
typedef float f32x4 __attribute__((ext_vector_type(4)));

__device__ __forceinline__ f32x4 mfma16(bf16x8 a, bf16x8 b, f32x4 c) {
  return __builtin_amdgcn_mfma_f32_16x16x32_bf16(a, b, c, 0, 0, 0);
}

// async global->LDS, 16B per lane. LDS dest = wave-uniform base + lane*16 (HW rule).
__device__ __forceinline__ void gl_lds16(const void* g, void* lds) {
  auto* lp = reinterpret_cast<__attribute__((address_space(3))) unsigned int*>(
      reinterpret_cast<uintptr_t>(lds));
  const auto* gp = reinterpret_cast<const __attribute__((address_space(1))) unsigned int*>(
      reinterpret_cast<uintptr_t>(g));
  __builtin_amdgcn_global_load_lds(gp, lp, 16, 0, 0);
}

// ---------------- transpose + f32->bf16 convert: out[c][r] = (bf16) in[r][c] ----------------
__global__ __launch_bounds__(256) void tconv(const float* __restrict__ in,
                                             bf16* __restrict__ out, int R, int C) {
  in  += (size_t)blockIdx.z * R * C;
  out += (size_t)blockIdx.z * R * C;
  __shared__ float t[32][33];
  const int r0 = blockIdx.x * 32, c0 = blockIdx.y * 32;
  const int lx = threadIdx.x & 31, ly = threadIdx.x >> 5;
#pragma unroll
  for (int q = 0; q < 4; q++)
    t[ly + q * 8][lx] = in[(size_t)(r0 + ly + q * 8) * C + c0 + lx];
  __syncthreads();
#pragma unroll
  for (int q = 0; q < 4; q++) {
    int c = ly + q * 8;
    out[(size_t)(c0 + c) * R + r0 + lx] = (bf16)t[lx][c];
  }
}

// both weight transposes in one launch (z selects the pair)
__global__ __launch_bounds__(256) void wconv(const float* __restrict__ in0,
                                             const float* __restrict__ in1,
                                             bf16* __restrict__ out0,
                                             bf16* __restrict__ out1) {
  const float* in = blockIdx.z ? in1 : in0;
  bf16* out = blockIdx.z ? out1 : out0;
  __shared__ float t[32][33];
  const int r0 = blockIdx.x * 32, c0 = blockIdx.y * 32;
  const int lx = threadIdx.x & 31, ly = threadIdx.x >> 5;
#pragma unroll
  for (int q = 0; q < 4; q++)
    t[ly + q * 8][lx] = in[(size_t)(r0 + ly + q * 8) * E_ + c0 + lx];
  __syncthreads();
#pragma unroll
  for (int q = 0; q < 4; q++) {
    int c = ly + q * 8;
    out[(size_t)(c0 + c) * E_ + r0 + lx] = (bf16)t[lx][c];
  }
}

// ---------------- GEMM: C[m][n] = sum_k A[m][k] * Bt[n][k]  (both bf16, K-contiguous) -------
// BM=256 x BN=128, 512 threads (8 waves, each 64x64), BK=32.
// 3-buffer counted-vmcnt pipeline, raw s_barrier, XCD-chunk block remap (32 tiles/XCD).
// LDS layout: rows of 64B (4 granules); rows [0,256)=A, [256,384)=B; slot XOR swizzle.
template <int EPI>
__global__ __launch_bounds__(512) void gemm_bt(const bf16* __restrict__ A,
                                               const bf16* __restrict__ Bt,
                                               bf16* __restrict__ outT,
                                               bf16* __restrict__ outD,
                                               float* __restrict__ outF,
                                               const float* __restrict__ bias) {
  constexpr int M = E_, N = L_, K = E_;
  constexpr int NIT = K / 32;
  // XCD-chunk remap: linear dispatch id -> (b, bm, bn) so each XCD owns 32
  // consecutive logical tiles ordered ((b,bm), bn): A panel stays L2-resident.
  const int lin = (int)blockIdx.x;                 // [0,256)
  const int lgc = (lin & 7) * 32 + (lin >> 3);     // bijective (256 = 8*32)
  const int bn = lgc & 15, bm = (lgc >> 4) & 3, b = lgc >> 6;
  __shared__ bf16 AB[3][384 * 32];                 // 3 x 24KB
  const int tid = threadIdx.x, w = tid >> 6, l = tid & 63;
  const int wm = (w >> 1) << 6, wn = (w & 1) << 6;
  const bf16* Ap = A + (size_t)bm * 256 * K;
  const bf16* Bp = Bt + (size_t)b * N * K + (size_t)bn * 128 * K;
  f32x4 acc[4][4] = {};
  // staging: lane t stages granules t (A rows 0-127), t+512 (A rows 128-255),
  // t+1024 (B rows 0-127); all share slot s (128,256 = 0 mod 4 in (row>>1)&3).
  const int rr = tid >> 2, s = (tid & 3) ^ ((rr >> 1) & 3);

#define STAGE_G(kt_, buf)                                                           \
  do {                                                                              \
    gl_lds16(Ap + (size_t)rr * K + (kt_) + s * 8, &AB[buf][(size_t)tid * 8]);       \
    gl_lds16(Ap + (size_t)(rr + 128) * K + (kt_) + s * 8,                           \
             &AB[buf][(size_t)(tid + 512) * 8]);                                    \
    gl_lds16(Bp + (size_t)rr * K + (kt_) + s * 8, &AB[buf][(size_t)(tid + 1024) * 8]); \
  } while (0)

  STAGE_G(0, 0);
  STAGE_G(32, 1);
  asm volatile("s_waitcnt vmcnt(3)" ::: "memory");  // tile 0 landed; tile 1 in flight
  __builtin_amdgcn_s_barrier();
#pragma unroll 1
  for (int it = 0; it < NIT; it++) {
    const int cur = it - (it / 3) * 3;  // it % 3
    if (it + 2 < NIT) STAGE_G((it + 2) * 32, (it + 2) - ((it + 2) / 3) * 3);
    bf16x8 af[4], bfr[4];
#pragma unroll
    for (int fm = 0; fm < 4; fm++) {
      int row = wm + fm * 16 + (l & 15);
      int gg = row * 4 + ((l >> 4) ^ ((row >> 1) & 3));
      af[fm] = *(const bf16x8*)(&AB[cur][gg * 8]);
    }
#pragma unroll
    for (int fn = 0; fn < 4; fn++) {
      int row = 256 + wn + fn * 16 + (l & 15);
      int gg = row * 4 + ((l >> 4) ^ ((row >> 1) & 3));
      bfr[fn] = *(const bf16x8*)(&AB[cur][gg * 8]);
    }
    __builtin_amdgcn_s_setprio(1);
#pragma unroll
    for (int fm = 0; fm < 4; fm++)
#pragma unroll
      for (int fn = 0; fn < 4; fn++)
        acc[fm][fn] = mfma16(af[fm], bfr[fn], acc[fm][fn]);
    __builtin_amdgcn_s_setprio(0);
    if (it + 2 < NIT) {
      asm volatile("s_waitcnt vmcnt(3)" ::: "memory");  // next tile landed, 3 in flight
    } else if (it + 1 < NIT) {
      asm volatile("s_waitcnt vmcnt(0)" ::: "memory");  // tail: drain
    }
    __builtin_amdgcn_s_barrier();
  }
#undef STAGE_G
  const int cm = bm * 256 + wm, cn = bn * 128 + wn;
  if (EPI == 0) {
#pragma unroll
    for (int fn = 0; fn < 4; fn++) {
#pragma unroll
      for (int fm = 0; fm < 4; fm++) {
        int n = cn + fn * 16 + (l & 15);
        int m = cm + fm * 16 + ((l >> 4) << 2);
        f32x4 v = acc[fm][fn];
        bf16x4 pv = {(bf16)v[0], (bf16)v[1], (bf16)v[2], (bf16)v[3]};
        *(bf16x4*)(outT + (size_t)b * N * M + (size_t)n * M + m) = pv;
#pragma unroll
        for (int r = 0; r < 4; r++)
          outD[(size_t)b * M * N + (size_t)(m + r) * N + n] = pv[r];
      }
    }
  } else {
#pragma unroll
    for (int fm = 0; fm < 4; fm++) {
      int m = cm + fm * 16 + ((l >> 4) << 2);
#pragma unroll
      for (int r = 0; r < 4; r++) {
        float bv = bias[m + r];
#pragma unroll
        for (int fn = 0; fn < 4; fn++) {
          int n = cn + fn * 16 + (l & 15);
          outF[(size_t)b * M * N + (size_t)(m + r) * N + n] = acc[fm][fn][r] + bv;
        }
      }
    }
  }
}

// ---------------- flash attention (causal over keys i<=j, softmax over i) -------------------
// QBLK=128 (8 waves x 16 rows), dbuf K/V prefetch, zero in-loop cross-lane reduces.
__global__ __launch_bounds__(512) void attn(const bf16* __restrict__ kqvT,
                                            const bf16* __restrict__ kqvD,
                                            bf16* __restrict__ tT) {
  const int linear = (int)blockIdx.x + 16 * ((int)blockIdx.y + 16 * (int)blockIdx.z);
  const int qb = 15 - (linear >> 6);
  const int h = linear & 15, b = (linear >> 4) & 3;
  const int tid = threadIdx.x, w = tid >> 6, l = tid & 63;
  const int j0 = qb * 128 + w * 16;
  __shared__ bf16 Ks[2][64 * 64];
  __shared__ bf16 Vs[2][64 * 64];
  __shared__ bf16 Ps[8][16 * 64];
  const size_t bT = (size_t)b * L_ * E_;
  const size_t bD = (size_t)b * E_ * L_;
  bf16x8 qa[2];
  {
    size_t qoff = bT + (size_t)(j0 + (l & 15)) * E_ + h * 64 + ((l >> 4) << 3);
    qa[0] = *(const bf16x8*)(kqvT + qoff);
    qa[1] = *(const bf16x8*)(kqvT + qoff + 32);
#pragma unroll
    for (int e = 0; e < 8; e++) {  // fold scale into Q (2^-5 exact in bf16)
      qa[0][e] = (bf16)((float)qa[0][e] * SCALE_);
      qa[1][e] = (bf16)((float)qa[1][e] * SCALE_);
    }
  }
  float mrun[4] = {0.f, 0.f, 0.f, 0.f};   // deferred max, guard at +8
  float lsum[4] = {0.f, 0.f, 0.f, 0.f};   // per-lane partial row-sums
  f32x4 tacc[4] = {};
  bf16* myPs = &Ps[w][0];
  const int g = w * 64 + l;
  const int rS = g >> 3, sS = (g & 7) ^ (rS & 7);
  const int nch = 2 * (qb + 1);

#define STAGE(c, buf)                                                                  \
  do {                                                                                 \
    const int i0_ = (c) * 64;                                                          \
    gl_lds16(kqvT + bT + (size_t)(i0_ + rS) * E_ + h * 64 + sS * 8, &Ks[buf][g * 8]);  \
    gl_lds16(kqvD + bD + (size_t)(h * 64 + rS) * L_ + i0_ + sS * 8, &Vs[buf][g * 8]);  \
  } while (0)

  STAGE(0, 0);
  asm volatile("s_waitcnt vmcnt(0)" ::: "memory");
  __syncthreads();

#pragma unroll 1
  for (int c = 0; c < nch; c++) {
    const int cur = c & 1;
    if (c + 1 < nch) STAGE(c + 1, cur ^ 1);  // prefetch next tile
    const int i0 = c * 64;
    const bf16* Kc = &Ks[cur][0];
    const bf16* Vc = &Vs[cur][0];
    if (i0 <= j0 + 15) {  // wave-uniform: skip fully-masked tiles
      f32x4 sacc[4];
      __builtin_amdgcn_s_setprio(1);
#pragma unroll
      for (int fi = 0; fi < 4; fi++) {
        int row = fi * 16 + (l & 15);
        bf16x8 k0 = *(const bf16x8*)(Kc + row * 64 + (((l >> 4) ^ (row & 7)) << 3));
        bf16x8 k1 = *(const bf16x8*)(Kc + row * 64 + ((((l >> 4) + 4) ^ (row & 7)) << 3));
        f32x4 z = {};
        z = mfma16(qa[0], k0, z);
        z = mfma16(qa[1], k1, z);
        sacc[fi] = z;
      }
      __builtin_amdgcn_s_setprio(0);
      const int jrb = j0 + ((l >> 4) << 2);
      if (i0 + 63 > j0) {  // tile touches the diagonal: causal mask
#pragma unroll
        for (int fi = 0; fi < 4; fi++) {
          int i = i0 + fi * 16 + (l & 15);
#pragma unroll
          for (int r = 0; r < 4; r++)
            if (i > jrb + r) sacc[fi][r] = -INFINITY;
        }
      }
      bool ov = false;
#pragma unroll
      for (int fi = 0; fi < 4; fi++)
#pragma unroll
        for (int r = 0; r < 4; r++) ov |= (sacc[fi][r] > mrun[r] + 8.f);
      if (__any(ov)) {  // cold: true rescale (never taken for this data)
        float mx[4];
#pragma unroll
        for (int r = 0; r < 4; r++)
          mx[r] = fmaxf(fmaxf(sacc[0][r], sacc[1][r]), fmaxf(sacc[2][r], sacc[3][r]));
#pragma unroll
        for (int r = 0; r < 4; r++) {
          mx[r] = fmaxf(mx[r], __shfl_xor(mx[r], 1));
          mx[r] = fmaxf(mx[r], __shfl_xor(mx[r], 2));
          mx[r] = fmaxf(mx[r], __shfl_xor(mx[r], 4));
          mx[r] = fmaxf(mx[r], __shfl_xor(mx[r], 8));
        }
#pragma unroll
        for (int r = 0; r < 4; r++) {
          float mn = fmaxf(mrun[r], mx[r]);
          float a = __expf(mrun[r] - mn);
          lsum[r] *= a;
#pragma unroll
          for (int fd = 0; fd < 4; fd++) tacc[fd][r] *= a;
          mrun[r] = mn;
        }
      }
#pragma unroll
      for (int fi = 0; fi < 4; fi++) {
        int icol = fi * 16 + (l & 15);
#pragma unroll
        for (int r = 0; r < 4; r++) {
          float p = __expf(sacc[fi][r] - mrun[r]);
          lsum[r] += p;
          int jl = ((l >> 4) << 2) + r;
          int slot = (icol >> 3) ^ (jl & 7);
          myPs[jl * 64 + slot * 8 + (icol & 7)] = (bf16)p;
        }
      }
      bf16x8 pa[2];
      {
        int jl = l & 15;
#pragma unroll
        for (int kc = 0; kc < 2; kc++)
          pa[kc] = *(const bf16x8*)(myPs + jl * 64 + (((kc * 4 + (l >> 4)) ^ (jl & 7)) << 3));
      }
      __builtin_amdgcn_s_setprio(1);
#pragma unroll
      for (int fd = 0; fd < 4; fd++) {
        int row = fd * 16 + (l & 15);
#pragma unroll
        for (int kc = 0; kc < 2; kc++) {
          bf16x8 vf = *(const bf16x8*)(Vc + row * 64 + (((kc * 4 + (l >> 4)) ^ (row & 7)) << 3));
          tacc[fd] = mfma16(pa[kc], vf, tacc[fd]);
        }
      }
      __builtin_amdgcn_s_setprio(0);
    }
    asm volatile("s_waitcnt vmcnt(0)" ::: "memory");  // prefetch landed
    __syncthreads();
  }
#undef STAGE
#pragma unroll
  for (int r = 0; r < 4; r++) {
    lsum[r] += __shfl_xor(lsum[r], 1);
    lsum[r] += __shfl_xor(lsum[r], 2);
    lsum[r] += __shfl_xor(lsum[r], 4);
    lsum[r] += __shfl_xor(lsum[r], 8);
  }
#pragma unroll
  for (int r = 0; r < 4; r++) {
    int j = j0 + ((l >> 4) << 2) + r;
    float inv = 1.0f / lsum[r];
#pragma unroll
    for (int fd = 0; fd < 4; fd++) {
      int d = fd * 16 + (l & 15);
      tT[bT + (size_t)j * E_ + h * 64 + d] = (bf16)(tacc[fd][r] * inv);
    }
  }
}

extern "C" void kernel_launch(void* const* d_in, const int* in_sizes, int n_in,
                              void* d_out, int out_size, void* d_ws, size_t ws_size,
                              hipStream_t stream) {
  const float* x     = (const float*)d_in[0];
  const float* Wqkv  = (const float*)d_in[1];
  const float* Wproj = (const float*)d_in[2];
  const float* bias  = (const float*)d_in[3];
  float* out = (float*)d_out;
  char* ws = (char*)d_ws;
  bf16* Wt_qkv  = (bf16*)ws;                         // 2 MB
  bf16* Wt_proj = (bf16*)(ws + (2ull << 20));        // 2 MB
  bf16* xT      = (bf16*)(ws + (4ull << 20));        // 16 MB (reused as tT)
  bf16* kqvT    = (bf16*)(ws + (20ull << 20));       // 16 MB
  bf16* kqvD    = (bf16*)(ws + (36ull << 20));       // 16 MB  -> total 52 MB
  bf16* tT      = xT;                                // alias: xT dead after gemm1

  wconv<<<dim3(32, 32, 2), 256, 0, stream>>>(Wqkv, Wproj, Wt_qkv, Wt_proj);
  tconv<<<dim3(32, 64, B_), 256, 0, stream>>>(x, xT, E_, L_);
  gemm_bt<0><<<dim3(256, 1, 1), 512, 0, stream>>>(Wt_qkv, xT, kqvT, kqvD,
                                                  (float*)nullptr, (const float*)nullptr);
  attn<<<dim3(16, 16, B_), 512, 0, stream>>>(kqvT, kqvD, tT);
  gemm_bt<1><<<dim3(256, 1, 1), 512, 0, stream>>>(Wt_proj, tT, (bf16*)nullptr,
                                                  (bf16*)nullptr, out, bias);
}